// Round 2
// baseline (393.436 us; speedup 1.0000x reference)
//
#include <hip/hip_runtime.h>
#include <cstdint>

// Problem: y[16384,2048] = x[16384,2048](f32) @ W[2048,2048](int8-valued, [in,out]) * scale[1,2048]
// NOTE: harness materializes integer inputs as int32 -> read weight as const int*.
// Strategy: x -> f16 (RNE; error analysis shows 60x margin vs threshold), W -> f16 exact,
// single-pass f16 MFMA GEMM, fp32 accumulate. m97 structure: 128x128 tile, BK=32,
// global_load_lds width-16 DMA staging.

#define M_TOK 16384
#define K_DIM 2048
#define N_DIM 2048
#define BK 32

typedef _Float16 f16;
typedef f16 f16x4 __attribute__((ext_vector_type(4)));
typedef f16 f16x8 __attribute__((ext_vector_type(8)));
typedef float f32x4 __attribute__((ext_vector_type(4)));

// ---------------------------------------------------------------------------
// Pre-pass 1: x fp32 -> f16 (RNE). Memory-bound: 134MB read + 67MB write.
// ---------------------------------------------------------------------------
__global__ void convert_x_kernel(const float* __restrict__ x, f16* __restrict__ xh) {
  const int n4 = (M_TOK * K_DIM) / 4;
  const int stride = gridDim.x * blockDim.x;
  for (int i = blockIdx.x * blockDim.x + threadIdx.x; i < n4; i += stride) {
    float4 v = ((const float4*)x)[i];
    f16x4 h;
    h[0] = (f16)v.x; h[1] = (f16)v.y; h[2] = (f16)v.z; h[3] = (f16)v.w;
    ((f16x4*)xh)[i] = h;
  }
}

// ---------------------------------------------------------------------------
// Pre-pass 2: W int32 [K][N] -> W^T f16 [N][K] (tiled transpose; |w|<=128 exact in f16)
// ---------------------------------------------------------------------------
__global__ void convert_w_kernel(const int* __restrict__ w, f16* __restrict__ wt) {
  __shared__ f16 tile[64][68];             // [n_local][k_local], padded
  const int tid = threadIdx.x;
  const int nb = blockIdx.x * 64;
  const int kb = blockIdx.y * 64;
  const int cq = tid & 15;                 // 4-wide column group
  const int rr = tid >> 4;                 // 0..15

#pragma unroll
  for (int g = 0; g < 4; ++g) {
    int krow = g * 16 + rr;
    const int* p = w + (size_t)(kb + krow) * N_DIM + nb + cq * 4;
    int4 v = *(const int4*)p;              // 4 int32 weights, coalesced along n
    tile[cq * 4 + 0][krow] = (f16)(float)v.x;
    tile[cq * 4 + 1][krow] = (f16)(float)v.y;
    tile[cq * 4 + 2][krow] = (f16)(float)v.z;
    tile[cq * 4 + 3][krow] = (f16)(float)v.w;
  }
  __syncthreads();
#pragma unroll
  for (int g = 0; g < 4; ++g) {
    int nrow = g * 16 + rr;
    f16x4 o;
#pragma unroll
    for (int j = 0; j < 4; ++j)
      o[j] = tile[nrow][cq * 4 + j];
    *(f16x4*)(wt + (size_t)(nb + nrow) * K_DIM + kb + cq * 4) = o;  // coalesced along k
  }
}

// ---------------------------------------------------------------------------
// Main GEMM: C = x_h * W, scaled. m97 structure, single f16 pass.
// ---------------------------------------------------------------------------
__device__ __forceinline__ void async_load16(const void* g, void* l) {
  // per-lane global address; LDS dest = wave-uniform base + lane*16
  __builtin_amdgcn_global_load_lds((__attribute__((address_space(1))) void*)g,
                                   (__attribute__((address_space(3))) void*)l,
                                   16, 0, 0);
}

__global__ __launch_bounds__(256) void gemm_f16(
    const f16* __restrict__ xh, const f16* __restrict__ wt,
    const float* __restrict__ scale, float* __restrict__ out) {
  __shared__ __align__(16) f16 sA[128 * BK];    // A tile [m][k] 8KB
  __shared__ __align__(16) f16 sB[128 * BK];    // B^T tile [n][k] 8KB

  const int tid = threadIdx.x;
  const int wave = tid >> 6;
  const int lane = tid & 63;
  const int m0 = blockIdx.y * 128;
  const int n0 = blockIdx.x * 128;
  const int wm = (wave & 1) * 64;          // wave's 64x64 sub-tile
  const int wn = (wave >> 1) * 64;

  // DMA staging: tile = 8 chunks of 1KB (16 rows); wave fills chunks {2w, 2w+1}.
  // chunk c, lane i -> LDS row c*16 + i/4, k-offset (i%4)*8  (lane*16B rule)
  const int c0 = wave * 2;
  const int rowA = c0 * 16 + (lane >> 2);
  const int kq8 = (lane & 3) * 8;

  const f16* gA0 = xh + (size_t)(m0 + rowA) * K_DIM + kq8;
  const f16* gA1 = xh + (size_t)(m0 + rowA + 16) * K_DIM + kq8;
  const f16* gB0 = wt + (size_t)(n0 + rowA) * K_DIM + kq8;
  const f16* gB1 = wt + (size_t)(n0 + rowA + 16) * K_DIM + kq8;

  f16* lA0 = sA + c0 * 512;  f16* lA1 = lA0 + 512;
  f16* lB0 = sB + c0 * 512;  f16* lB1 = lB0 + 512;

  // MFMA fragment geometry (16x16x32): A[m=lane&15][k=(lane>>4)*8+j]
  const int fr = lane & 15;
  const int fq = (lane >> 4) * 8;

  f32x4 acc[4][4] = {};

  for (int k0 = 0; k0 < K_DIM; k0 += BK) {
    async_load16(gA0 + k0, lA0);
    async_load16(gA1 + k0, lA1);
    async_load16(gB0 + k0, lB0);
    async_load16(gB1 + k0, lB1);
    __syncthreads();   // drains vmcnt -> DMA data visible

    f16x8 a[4], b[4];
#pragma unroll
    for (int t = 0; t < 4; ++t) {
      a[t] = *(const f16x8*)&sA[(wm + t * 16 + fr) * BK + fq];
      b[t] = *(const f16x8*)&sB[(wn + t * 16 + fr) * BK + fq];
    }
#pragma unroll
    for (int mm = 0; mm < 4; ++mm)
#pragma unroll
      for (int nn = 0; nn < 4; ++nn)
        acc[mm][nn] = __builtin_amdgcn_mfma_f32_16x16x32_f16(a[mm], b[nn], acc[mm][nn], 0, 0, 0);
    __syncthreads();   // protect LDS from next iter's DMA
  }

  // Epilogue: C/D layout col(n)=lane&15, row(m)=(lane>>4)*4+reg; apply scale[n]
#pragma unroll
  for (int nn = 0; nn < 4; ++nn) {
    int col = n0 + wn + nn * 16 + fr;
    float s = scale[col];
#pragma unroll
    for (int mm = 0; mm < 4; ++mm) {
      int rbase = m0 + wm + mm * 16 + (lane >> 4) * 4;
      f32x4 v = acc[mm][nn];
#pragma unroll
      for (int r = 0; r < 4; ++r)
        out[(size_t)(rbase + r) * N_DIM + col] = v[r] * s;
    }
  }
}

// ---------------------------------------------------------------------------
extern "C" void kernel_launch(void* const* d_in, const int* in_sizes, int n_in,
                              void* d_out, int out_size, void* d_ws, size_t ws_size,
                              hipStream_t stream) {
  const float* x     = (const float*)d_in[0];
  const float* scale = (const float*)d_in[1];
  const int* w       = (const int*)d_in[2];   // integer inputs arrive as int32
  float* out         = (float*)d_out;

  // workspace layout: x_h f16 (64MB) | W^T f16 (8MB) = 72MB
  char* ws = (char*)d_ws;
  f16* xh = (f16*)ws;
  f16* wt = (f16*)(ws + (size_t)M_TOK * K_DIM * 2);

  convert_x_kernel<<<8192, 256, 0, stream>>>(x, xh);
  convert_w_kernel<<<dim3(N_DIM / 64, K_DIM / 64), 256, 0, stream>>>(w, wt);
  // grid x = n-tiles (16) fastest -> consecutive blocks share the A row-strip (L2/L3 reuse)
  gemm_f16<<<dim3(N_DIM / 128, M_TOK / 128), 256, 0, stream>>>(xh, wt, scale, out);
}